// Round 1
// baseline (204.722 us; speedup 1.0000x reference)
//
#include <hip/hip_runtime.h>
#include <math.h>

// CalWeight: out[b,j] = phi[b,j] - phi[b,(j+1)%N]
//   phi[b,j] = atan2f(verts_y[b,j] - row[b], verts_x[b,j] - col[b])
// x layout per row: [col, row, v0x, v0y, v1x, v1y, ... v1023x, v1023y]
// N = 1024 vertices, row stride = 2 + 2*N = 2050 floats.

#define NVERT 1024
#define ROWSTRIDE (2 + 2 * NVERT)
#define BLK 256

__global__ __launch_bounds__(BLK) void calweight_kernel(const float* __restrict__ x,
                                                        float* __restrict__ out) {
    const int b = blockIdx.x;
    const int t = threadIdx.x;

    const float* __restrict__ xr = x + (size_t)b * ROWSTRIDE;
    const float colv = xr[0];
    const float rowv = xr[1];

    __shared__ float phi[NVERT];

    // Phase 1: coalesced float2 loads (one vertex per load), compute phi.
    // (b*2050 + 2)*4 bytes is always 8B-aligned, so float2* cast is safe.
    const float2* __restrict__ verts = (const float2*)(xr + 2);
#pragma unroll
    for (int k = 0; k < NVERT / BLK; ++k) {
        const int j = t + k * BLK;
        const float2 v = verts[j];
        phi[j] = atan2f(v.y - rowv, v.x - colv);
    }
    __syncthreads();

    // Phase 2: each thread produces 4 consecutive outputs as one float4 store.
    float* __restrict__ orow = out + (size_t)b * NVERT;
    const int j0 = 4 * t;
    const float4 p = ((const float4*)phi)[t];
    const float pn = phi[(j0 + 4) & (NVERT - 1)];  // wrap: j=1023 -> phi[0]
    float4 r;
    r.x = p.x - p.y;
    r.y = p.y - p.z;
    r.z = p.z - p.w;
    r.w = p.w - pn;
    ((float4*)orow)[t] = r;
}

extern "C" void kernel_launch(void* const* d_in, const int* in_sizes, int n_in,
                              void* d_out, int out_size, void* d_ws, size_t ws_size,
                              hipStream_t stream) {
    const float* x = (const float*)d_in[0];
    float* out = (float*)d_out;
    const int B = in_sizes[0] / ROWSTRIDE;  // 16384
    calweight_kernel<<<B, BLK, 0, stream>>>(x, out);
}